// Round 1
// baseline (1134.661 us; speedup 1.0000x reference)
//
#include <hip/hip_runtime.h>
#include <stdint.h>

#define NTOK 8192   // B*T
#define DDIM 1024
#define LDIM 512
#define VCB  8192
#define MROWS 16384 // NTOK + VCB

typedef unsigned long long u64;

// ---- workspace layout (bytes) ----
#define OFF_P      0ull
#define OFF_Q      (OFF_P + (u64)MROWS * LDIM * 4)
#define OFF_B2     (OFF_Q + (u64)MROWS * LDIM * 4)
#define OFF_PACKED (OFF_B2 + (u64)VCB * 4)
#define OFF_HIST   (OFF_PACKED + (u64)NTOK * 8)
#define OFF_PARTQ  (OFF_HIST + (u64)VCB * 4)
#define OFF_PARTL  (OFF_PARTQ + (u64)NTOK * 4)

__device__ __forceinline__ unsigned key_of(float f) {
  unsigned u = __float_as_uint(f);
  return (u & 0x80000000u) ? ~u : (u | 0x80000000u);
}

__device__ __forceinline__ u64 shfl_xor_u64_w16(u64 v, int m) {
  unsigned lo = (unsigned)__shfl_xor((int)(unsigned)v, m, 16);
  unsigned hi = (unsigned)__shfl_xor((int)(v >> 32), m, 16);
  return (((u64)hi) << 32) | lo;
}

// ---------------- init ----------------
__global__ __launch_bounds__(256)
void k_init(u64* __restrict__ packed, int* __restrict__ hist) {
  int i = blockIdx.x * 256 + threadIdx.x;
  if (i < NTOK) packed[i] = ~0ull;
  if (i < VCB) hist[i] = 0;
}

// ---------------- latent GEMM: P = A @ W + b ----------------
// rows 0..NTOK-1: x @ W_in + b_in ; rows NTOK..: codebook @ W_code + b_code
__global__ __launch_bounds__(256, 2)
void k_latent_gemm(const float* __restrict__ x, const float* __restrict__ cb,
                   const float* __restrict__ Wi, const float* __restrict__ bi,
                   const float* __restrict__ Wc, const float* __restrict__ bc,
                   float* __restrict__ P) {
  constexpr int BM = 128, BK = 16;
  __shared__ float As[BK][BM + 4];
  __shared__ float Bs[BK][BM + 4];
  const int t = threadIdx.x;
  const int tx = t & 15, ty = t >> 4;
  const int row0 = blockIdx.y * BM;
  const int col0 = blockIdx.x * BM;
  const bool isCode = (row0 >= NTOK);
  const float* A = isCode ? cb : x;
  const float* W = isCode ? Wc : Wi;
  const float* bias = isCode ? bc : bi;
  const int ar0 = isCode ? (row0 - NTOK) : row0;

  float acc[8][8];
#pragma unroll
  for (int i = 0; i < 8; ++i)
#pragma unroll
    for (int j = 0; j < 8; ++j) acc[i][j] = 0.f;

  const int lrow = t >> 1;          // 0..127
  const int lk = (t & 1) * 8;       // 0 or 8
  const float* ap = A + (size_t)(ar0 + lrow) * DDIM + lk;
  const int wk = t >> 4;            // 0..15
  const int wn = (t & 15) * 8;      // 0..120
  const float* wp = W + (size_t)wk * LDIM + col0 + wn;

  for (int k0 = 0; k0 < DDIM; k0 += BK) {
    float4 a0 = *(const float4*)(ap + k0);
    float4 a1 = *(const float4*)(ap + k0 + 4);
    float4 w0 = *(const float4*)(wp + (size_t)k0 * LDIM);
    float4 w1 = *(const float4*)(wp + (size_t)k0 * LDIM + 4);
    __syncthreads();
    As[lk + 0][lrow] = a0.x; As[lk + 1][lrow] = a0.y;
    As[lk + 2][lrow] = a0.z; As[lk + 3][lrow] = a0.w;
    As[lk + 4][lrow] = a1.x; As[lk + 5][lrow] = a1.y;
    As[lk + 6][lrow] = a1.z; As[lk + 7][lrow] = a1.w;
    *(float4*)&Bs[wk][wn] = w0;
    *(float4*)&Bs[wk][wn + 4] = w1;
    __syncthreads();
#pragma unroll
    for (int k = 0; k < BK; ++k) {
      float4 a0r = *(const float4*)&As[k][ty * 8];
      float4 a1r = *(const float4*)&As[k][ty * 8 + 4];
      float4 b0r = *(const float4*)&Bs[k][tx * 4];
      float4 b1r = *(const float4*)&Bs[k][64 + tx * 4];
      float av[8] = {a0r.x, a0r.y, a0r.z, a0r.w, a1r.x, a1r.y, a1r.z, a1r.w};
      float bv[8] = {b0r.x, b0r.y, b0r.z, b0r.w, b1r.x, b1r.y, b1r.z, b1r.w};
#pragma unroll
      for (int i = 0; i < 8; ++i)
#pragma unroll
        for (int j = 0; j < 8; ++j)
          acc[i][j] = fmaf(av[i], bv[j], acc[i][j]);
    }
  }

  float bvj[8];
#pragma unroll
  for (int j = 0; j < 4; ++j) {
    bvj[j]     = bias[col0 + tx * 4 + j];
    bvj[4 + j] = bias[col0 + 64 + tx * 4 + j];
  }
#pragma unroll
  for (int i = 0; i < 8; ++i) {
    int r = row0 + ty * 8 + i;
    float4 o0 = make_float4(acc[i][0] + bvj[0], acc[i][1] + bvj[1],
                            acc[i][2] + bvj[2], acc[i][3] + bvj[3]);
    float4 o1 = make_float4(acc[i][4] + bvj[4], acc[i][5] + bvj[5],
                            acc[i][6] + bvj[6], acc[i][7] + bvj[7]);
    *(float4*)&P[(size_t)r * LDIM + col0 + tx * 4] = o0;
    *(float4*)&P[(size_t)r * LDIM + col0 + 64 + tx * 4] = o1;
  }
}

// ---------------- row normalize + b2 ----------------
__global__ __launch_bounds__(256)
void k_rownorm(const float* __restrict__ P, float* __restrict__ Q,
               float* __restrict__ b2) {
  const int row = blockIdx.x;
  const int t = threadIdx.x;
  const int lane = t & 63, wid = t >> 6;
  __shared__ float red[4];
  __shared__ float bcast;
  float v0 = P[(size_t)row * LDIM + t];
  float v1 = P[(size_t)row * LDIM + t + 256];
  float s = fmaf(v0, v0, v1 * v1);
#pragma unroll
  for (int o = 32; o > 0; o >>= 1) s += __shfl_down(s, o, 64);
  if (lane == 0) red[wid] = s;
  __syncthreads();
  if (t == 0) {
    float tot = red[0] + red[1] + red[2] + red[3];
    bcast = (float)(1.0 / sqrt((double)tot + 1e-12));
  }
  __syncthreads();
  float rs = bcast;
  float q0 = v0 * rs, q1 = v1 * rs;
  Q[(size_t)row * LDIM + t] = q0;
  Q[(size_t)row * LDIM + t + 256] = q1;
  if (row >= NTOK) {
    // b2 computed like the reference: fp32 sum of squares of the
    // *normalized* (rounded) values
    float s2 = fmaf(q0, q0, q1 * q1);
#pragma unroll
    for (int o = 32; o > 0; o >>= 1) s2 += __shfl_down(s2, o, 64);
    __syncthreads();
    if (lane == 0) red[wid] = s2;
    __syncthreads();
    if (t == 0) b2[row - NTOK] = red[0] + red[1] + red[2] + red[3];
  }
}

// ---------------- distance GEMM + fused argmin ----------------
__global__ __launch_bounds__(256, 2)
void k_dist_argmin(const float* __restrict__ Q, const float* __restrict__ b2,
                   u64* __restrict__ packed) {
  constexpr int BM = 128, BK = 16;
  __shared__ float As[BK][BM + 4];
  __shared__ float Bs[BK][BM + 4];
  const int t = threadIdx.x;
  const int tx = t & 15, ty = t >> 4;
  const int n0 = blockIdx.y * BM;
  const int v0 = blockIdx.x * BM;
  const float* Qin = Q;
  const float* Qcb = Q + (size_t)NTOK * LDIM;

  float acc[8][8];
#pragma unroll
  for (int i = 0; i < 8; ++i)
#pragma unroll
    for (int j = 0; j < 8; ++j) acc[i][j] = 0.f;

  const int lrow = t >> 1;
  const int lk = (t & 1) * 8;
  const float* ap = Qin + (size_t)(n0 + lrow) * LDIM + lk;
  const float* bp = Qcb + (size_t)(v0 + lrow) * LDIM + lk;

  for (int k0 = 0; k0 < LDIM; k0 += BK) {
    float4 a0 = *(const float4*)(ap + k0);
    float4 a1 = *(const float4*)(ap + k0 + 4);
    float4 b0 = *(const float4*)(bp + k0);
    float4 b1 = *(const float4*)(bp + k0 + 4);
    __syncthreads();
    As[lk + 0][lrow] = a0.x; As[lk + 1][lrow] = a0.y;
    As[lk + 2][lrow] = a0.z; As[lk + 3][lrow] = a0.w;
    As[lk + 4][lrow] = a1.x; As[lk + 5][lrow] = a1.y;
    As[lk + 6][lrow] = a1.z; As[lk + 7][lrow] = a1.w;
    Bs[lk + 0][lrow] = b0.x; Bs[lk + 1][lrow] = b0.y;
    Bs[lk + 2][lrow] = b0.z; Bs[lk + 3][lrow] = b0.w;
    Bs[lk + 4][lrow] = b1.x; Bs[lk + 5][lrow] = b1.y;
    Bs[lk + 6][lrow] = b1.z; Bs[lk + 7][lrow] = b1.w;
    __syncthreads();
#pragma unroll
    for (int k = 0; k < BK; ++k) {
      float4 a0r = *(const float4*)&As[k][ty * 8];
      float4 a1r = *(const float4*)&As[k][ty * 8 + 4];
      float4 b0r = *(const float4*)&Bs[k][tx * 4];
      float4 b1r = *(const float4*)&Bs[k][64 + tx * 4];
      float av[8] = {a0r.x, a0r.y, a0r.z, a0r.w, a1r.x, a1r.y, a1r.z, a1r.w};
      float bv[8] = {b0r.x, b0r.y, b0r.z, b0r.w, b1r.x, b1r.y, b1r.z, b1r.w};
#pragma unroll
      for (int i = 0; i < 8; ++i)
#pragma unroll
        for (int j = 0; j < 8; ++j)
          acc[i][j] = fmaf(av[i], bv[j], acc[i][j]);
    }
  }

  float b2v[8];
#pragma unroll
  for (int j = 0; j < 4; ++j) {
    b2v[j]     = b2[v0 + tx * 4 + j];
    b2v[4 + j] = b2[v0 + 64 + tx * 4 + j];
  }
#pragma unroll
  for (int i = 0; i < 8; ++i) {
    float bk = 1e30f;
    int bvi = 0;
#pragma unroll
    for (int j = 0; j < 8; ++j) {
      int col = (j < 4) ? (v0 + tx * 4 + j) : (v0 + 64 + tx * 4 + (j - 4));
      float key = fmaf(-2.f, acc[i][j], b2v[j]);  // a2[n] constant per row: drop
      if (key < bk) { bk = key; bvi = col; }
    }
    u64 pk = (((u64)key_of(bk)) << 32) | (unsigned)bvi;
#pragma unroll
    for (int m = 1; m < 16; m <<= 1) {
      u64 o = shfl_xor_u64_w16(pk, m);
      if (o < pk) pk = o;
    }
    if (tx == 0) atomicMin(&packed[n0 + ty * 8 + i], pk);
  }
}

// ---------------- gather + hist + loss partials ----------------
__global__ __launch_bounds__(256)
void k_gather(const u64* __restrict__ packed, const float* __restrict__ cb,
              const float* __restrict__ x, const float* __restrict__ P,
              float* __restrict__ out, int* __restrict__ hist,
              float* __restrict__ partq, float* __restrict__ partl) {
  const int n = blockIdx.x;
  const int t = threadIdx.x;
  const int lane = t & 63, wid = t >> 6;
  __shared__ int sIdx;
  __shared__ float rq[4], rl[4];
  if (t == 0) {
    int iv = (int)(packed[n] & 0xffffffffull);
    sIdx = iv;
    atomicAdd(&hist[iv], 1);
  }
  __syncthreads();
  const int iv = sIdx;
  float sq = 0.f;
  for (int c = t; c < DDIM; c += 256) {
    float q = cb[(size_t)iv * DDIM + c];
    float xv = x[(size_t)n * DDIM + c];
    out[(size_t)n * DDIM + c] = q;  // quantized_st == quantized numerically
    float d = q - xv;
    sq = fmaf(d, d, sq);
  }
  float sl = 0.f;
  for (int c = t; c < LDIM; c += 256) {
    float lq = P[(size_t)(NTOK + iv) * LDIM + c]; // latent_quantized = P_code[iv]
    float lx = P[(size_t)n * LDIM + c];           // latent_x = P_in[n]
    float d = lq - lx;
    sl = fmaf(d, d, sl);
  }
#pragma unroll
  for (int o = 32; o > 0; o >>= 1) {
    sq += __shfl_down(sq, o, 64);
    sl += __shfl_down(sl, o, 64);
  }
  if (lane == 0) { rq[wid] = sq; rl[wid] = sl; }
  __syncthreads();
  if (t == 0) {
    partq[n] = rq[0] + rq[1] + rq[2] + rq[3];
    partl[n] = rl[0] + rl[1] + rl[2] + rl[3];
  }
}

// ---------------- finalize scalars ----------------
__global__ __launch_bounds__(1024)
void k_final(const int* __restrict__ hist, const float* __restrict__ partq,
             const float* __restrict__ partl, float* __restrict__ out) {
  const int t = threadIdx.x;
  const int lane = t & 63, wid = t >> 6;  // 16 waves
  float perp = 0.f, usedf = 0.f, sq = 0.f, sl = 0.f;
  for (int v = t; v < VCB; v += 1024) {
    int h = hist[v];
    usedf += (h > 0) ? 1.f : 0.f;
    float p = (float)h * (1.f / (float)NTOK);
    perp -= p * logf(p + 1e-10f);
  }
  for (int n = t; n < NTOK; n += 1024) {
    sq += partq[n];
    sl += partl[n];
  }
#pragma unroll
  for (int o = 32; o > 0; o >>= 1) {
    perp  += __shfl_down(perp, o, 64);
    usedf += __shfl_down(usedf, o, 64);
    sq    += __shfl_down(sq, o, 64);
    sl    += __shfl_down(sl, o, 64);
  }
  __shared__ float red[16][4];
  if (lane == 0) {
    red[wid][0] = perp; red[wid][1] = usedf; red[wid][2] = sq; red[wid][3] = sl;
  }
  __syncthreads();
  if (t == 0) {
    float Pp = 0.f, U = 0.f, SQ = 0.f, SL = 0.f;
    for (int w = 0; w < 16; ++w) {
      Pp += red[w][0]; U += red[w][1]; SQ += red[w][2]; SL += red[w][3];
    }
    float mseq = SQ / (float)((size_t)NTOK * DDIM);
    float msel = SL / (float)((size_t)NTOK * LDIM);
    // _train_loss twice: (0.25 + 1.0) * mse each, + 0.1 * log_perplexity
    float loss = 1.25f * mseq + 1.25f * msel + 0.1f * Pp;
    out[(size_t)NTOK * DDIM + 0] = loss;
    out[(size_t)NTOK * DDIM + 1] = expf(Pp);
    out[(size_t)NTOK * DDIM + 2] = U / (float)VCB;
  }
}

extern "C" void kernel_launch(void* const* d_in, const int* in_sizes, int n_in,
                              void* d_out, int out_size, void* d_ws, size_t ws_size,
                              hipStream_t stream) {
  const float* x  = (const float*)d_in[0];
  const float* cb = (const float*)d_in[1];
  const float* Wi = (const float*)d_in[2];
  const float* bi = (const float*)d_in[3];
  const float* Wc = (const float*)d_in[4];
  const float* bc = (const float*)d_in[5];
  float* out = (float*)d_out;
  char* ws = (char*)d_ws;
  float* P      = (float*)(ws + OFF_P);
  float* Q      = (float*)(ws + OFF_Q);
  float* b2     = (float*)(ws + OFF_B2);
  u64*   packed = (u64*)(ws + OFF_PACKED);
  int*   hist   = (int*)(ws + OFF_HIST);
  float* partq  = (float*)(ws + OFF_PARTQ);
  float* partl  = (float*)(ws + OFF_PARTL);

  hipLaunchKernelGGL(k_init, dim3(32), dim3(256), 0, stream, packed, hist);
  hipLaunchKernelGGL(k_latent_gemm, dim3(LDIM / 128, MROWS / 128), dim3(256), 0,
                     stream, x, cb, Wi, bi, Wc, bc, P);
  hipLaunchKernelGGL(k_rownorm, dim3(MROWS), dim3(256), 0, stream, P, Q, b2);
  hipLaunchKernelGGL(k_dist_argmin, dim3(VCB / 128, NTOK / 128), dim3(256), 0,
                     stream, Q, b2, packed);
  hipLaunchKernelGGL(k_gather, dim3(NTOK), dim3(256), 0, stream, packed, cb, x,
                     P, out, hist, partq, partl);
  hipLaunchKernelGGL(k_final, dim3(1), dim3(1024), 0, stream, hist, partq,
                     partl, out);
}

// Round 2
// 302.778 us; speedup vs baseline: 3.7475x; 3.7475x over previous
//
#include <hip/hip_runtime.h>
#include <stdint.h>

#define NTOK 8192   // B*T
#define DDIM 1024
#define LDIM 512
#define VCB  8192
#define MROWS 16384 // NTOK + VCB

typedef unsigned long long u64;
typedef unsigned short ushort_t;
typedef float f32x4 __attribute__((ext_vector_type(4)));
typedef short s16x8 __attribute__((ext_vector_type(8)));

// ---- workspace layout (bytes) ----
#define OFF_P      0ull                                   // MROWS*LDIM fp32 = 33.5 MB
#define OFF_Q      (OFF_P + (u64)MROWS * LDIM * 4)        // MROWS*LDIM bf16 = 16.8 MB
#define OFF_WT     (OFF_Q + (u64)MROWS * LDIM * 2)        // 2*LDIM*DDIM bf16 = 2 MB
#define OFF_B2     (OFF_WT + (u64)2 * LDIM * DDIM * 2)    // VCB fp32
#define OFF_PART   (OFF_B2 + (u64)VCB * 4)                // NTOK*128 u64 = 8 MB
#define OFF_IDX    (OFF_PART + (u64)NTOK * 128 * 8)       // NTOK int
#define OFF_HIST   (OFF_IDX + (u64)NTOK * 4)              // VCB int
#define OFF_PARTQ  (OFF_HIST + (u64)VCB * 4)              // NTOK fp32
#define OFF_PARTL  (OFF_PARTQ + (u64)NTOK * 4)            // NTOK fp32

__device__ __forceinline__ unsigned key_of(float f) {
  unsigned u = __float_as_uint(f);
  return (u & 0x80000000u) ? ~u : (u | 0x80000000u);
}

__device__ __forceinline__ ushort_t f2bf(float f) {
  unsigned u = __float_as_uint(f);
  unsigned r = (u + 0x7fffu + ((u >> 16) & 1u)) >> 16;
  return (ushort_t)r;
}
__device__ __forceinline__ float bf2f(ushort_t b) {
  return __uint_as_float(((unsigned)b) << 16);
}

__device__ __forceinline__ u64 shfl_xor_u64(u64 v, int m, int w) {
  unsigned lo = (unsigned)__shfl_xor((int)(unsigned)v, m, w);
  unsigned hi = (unsigned)__shfl_xor((int)(v >> 32), m, w);
  return (((u64)hi) << 32) | lo;
}

__device__ __forceinline__ void gload_lds16(const void* g, void* l) {
  __builtin_amdgcn_global_load_lds(
      (const __attribute__((address_space(1))) unsigned int*)g,
      (__attribute__((address_space(3))) unsigned int*)l, 16, 0, 0);
}

__device__ __forceinline__ f32x4 mfma16(s16x8 a, s16x8 b, f32x4 c) {
  return __builtin_amdgcn_mfma_f32_16x16x32_bf16(a, b, c, 0, 0, 0);
}

// ---------------- init ----------------
__global__ __launch_bounds__(256)
void k_init(int* __restrict__ hist) {
  int i = blockIdx.x * 256 + threadIdx.x;
  if (i < VCB) hist[i] = 0;
}

// ---------------- W transpose + bf16 cast: Wt[n][k] = W[k][n] ----------------
// W: [DDIM][LDIM] fp32, Wt: [LDIM][DDIM] bf16. blockDim (32,8), grid (32,16,2)
__global__ __launch_bounds__(256)
void k_wt(const float* __restrict__ Wi, const float* __restrict__ Wc,
          ushort_t* __restrict__ Wt) {
  __shared__ float tile[32][33];
  const float* W = blockIdx.z ? Wc : Wi;
  ushort_t* O = Wt + (blockIdx.z ? (size_t)LDIM * DDIM : 0);
  const int k0 = blockIdx.x * 32, n0 = blockIdx.y * 32;
  const int tx = threadIdx.x, ty = threadIdx.y;
#pragma unroll
  for (int i = 0; i < 4; ++i)
    tile[ty * 4 + i][tx] = W[(size_t)(k0 + ty * 4 + i) * LDIM + n0 + tx];
  __syncthreads();
#pragma unroll
  for (int i = 0; i < 4; ++i)
    O[(size_t)(n0 + ty * 4 + i) * DDIM + k0 + tx] = f2bf(tile[tx][ty * 4 + i]);
}

// ---------------- latent GEMM (MFMA): P = A @ W + b ----------------
// rows 0..NTOK-1: x @ W_in + b_in ; rows NTOK..: codebook @ W_code + b_code
// A fp32 (converted in staging), W bf16 pre-transposed (Wt[n][k]).
__global__ __launch_bounds__(256)
void k_latent(const float* __restrict__ x, const float* __restrict__ cb,
              const ushort_t* __restrict__ Wt, const float* __restrict__ bi,
              const float* __restrict__ bc, float* __restrict__ P) {
  __shared__ __align__(16) ushort_t As[128 * 32];
  __shared__ __align__(16) ushort_t Bs[128 * 32];
  const int t = threadIdx.x;
  const int wave = t >> 6, lane = t & 63;
  const int col0 = blockIdx.x * 128;   // L index
  const int m0 = blockIdx.y * 128;     // row index in [0, MROWS)
  const bool isCode = (m0 >= NTOK);
  const float* A = isCode ? (cb + (size_t)(m0 - NTOK) * DDIM)
                          : (x + (size_t)m0 * DDIM);
  const ushort_t* W = Wt + (isCode ? (size_t)LDIM * DDIM : 0);
  const float* bias = isCode ? bc : bi;

  // A staging (manual fp32->bf16): thread t handles granule (t&3) of rows
  // (t>>2) and (t>>2)+64. Swizzled LDS position p = g ^ (r&3) ^ ((r>>2)&3).
  const int ar = t >> 2, ag = t & 3;
  const int apos = (ag ^ (ar & 3) ^ ((ar >> 2) & 3)) * 16;
  const float* aptr0 = A + (size_t)ar * DDIM + ag * 8;
  const float* aptr1 = A + (size_t)(ar + 64) * DDIM + ag * 8;
  char* aw0 = (char*)As + ar * 64 + apos;
  char* aw1 = (char*)As + (ar + 64) * 64 + apos;

  // B staging via global_load_lds: LDS slot l -> (row l>>2, pos l&3); source
  // granule g = (l&3) ^ ((l>>2)&3) ^ ((l>>4)&3). Wave w stages rows w*16, 64+w*16.
  const int srow = lane >> 2;
  const int sg = (lane & 3) ^ (srow & 3) ^ ((srow >> 2) & 3);
  const int r0a = wave * 16, r0b = 64 + wave * 16;
  const ushort_t* bptrA = W + (size_t)(col0 + r0a + srow) * DDIM + sg * 8;
  const ushort_t* bptrB = W + (size_t)(col0 + r0b + srow) * DDIM + sg * 8;
  char* bwA = (char*)Bs + r0a * 64;
  char* bwB = (char*)Bs + r0b * 64;

  const int wm = wave >> 1, wn = wave & 1;
  const int m = lane & 15, q = lane >> 4;
  const int pq = (q ^ (m & 3) ^ ((m >> 2) & 3)) * 16;

  f32x4 acc[4][4];
#pragma unroll
  for (int i = 0; i < 4; ++i)
#pragma unroll
    for (int j = 0; j < 4; ++j) acc[i][j] = (f32x4)(0.f);

  for (int k0 = 0; k0 < DDIM; k0 += 32) {
    float4 u0 = *(const float4*)(aptr0 + k0);
    float4 u1 = *(const float4*)(aptr0 + k0 + 4);
    float4 u2 = *(const float4*)(aptr1 + k0);
    float4 u3 = *(const float4*)(aptr1 + k0 + 4);
    __syncthreads();
    gload_lds16(bptrA + k0, bwA);
    gload_lds16(bptrB + k0, bwB);
    s16x8 a0, a1;
    a0[0] = (short)f2bf(u0.x); a0[1] = (short)f2bf(u0.y);
    a0[2] = (short)f2bf(u0.z); a0[3] = (short)f2bf(u0.w);
    a0[4] = (short)f2bf(u1.x); a0[5] = (short)f2bf(u1.y);
    a0[6] = (short)f2bf(u1.z); a0[7] = (short)f2bf(u1.w);
    a1[0] = (short)f2bf(u2.x); a1[1] = (short)f2bf(u2.y);
    a1[2] = (short)f2bf(u2.z); a1[3] = (short)f2bf(u2.w);
    a1[4] = (short)f2bf(u3.x); a1[5] = (short)f2bf(u3.y);
    a1[6] = (short)f2bf(u3.z); a1[7] = (short)f2bf(u3.w);
    *(s16x8*)aw0 = a0;
    *(s16x8*)aw1 = a1;
    __syncthreads();
    s16x8 af[4], bfr[4];
#pragma unroll
    for (int i = 0; i < 4; ++i)
      af[i] = *(const s16x8*)((const char*)As + (wm * 64 + i * 16 + m) * 64 + pq);
#pragma unroll
    for (int j = 0; j < 4; ++j)
      bfr[j] = *(const s16x8*)((const char*)Bs + (wn * 64 + j * 16 + m) * 64 + pq);
#pragma unroll
    for (int i = 0; i < 4; ++i)
#pragma unroll
      for (int j = 0; j < 4; ++j)
        acc[i][j] = mfma16(af[i], bfr[j], acc[i][j]);
  }

  float bv[4];
#pragma unroll
  for (int j = 0; j < 4; ++j) bv[j] = bias[col0 + wn * 64 + j * 16 + m];
#pragma unroll
  for (int i = 0; i < 4; ++i)
#pragma unroll
    for (int j = 0; j < 4; ++j) {
      int col = col0 + wn * 64 + j * 16 + m;
#pragma unroll
      for (int reg = 0; reg < 4; ++reg) {
        int row = m0 + wm * 64 + i * 16 + q * 4 + reg;
        P[(size_t)row * LDIM + col] = acc[i][j][reg] + bv[j];
      }
    }
}

// ---------------- row normalize: Q (bf16) + b2 ----------------
__global__ __launch_bounds__(256)
void k_rownorm(const float* __restrict__ P, ushort_t* __restrict__ Q,
               float* __restrict__ b2) {
  const int row = blockIdx.x;
  const int t = threadIdx.x;
  const int lane = t & 63, wid = t >> 6;
  __shared__ float red[4];
  __shared__ float bcast;
  float v0 = P[(size_t)row * LDIM + t];
  float v1 = P[(size_t)row * LDIM + t + 256];
  float s = fmaf(v0, v0, v1 * v1);
#pragma unroll
  for (int o = 32; o > 0; o >>= 1) s += __shfl_down(s, o, 64);
  if (lane == 0) red[wid] = s;
  __syncthreads();
  if (t == 0) {
    float tot = red[0] + red[1] + red[2] + red[3];
    bcast = (float)(1.0 / sqrt((double)tot + 1e-12));
  }
  __syncthreads();
  float rs = bcast;
  ushort_t q0 = f2bf(v0 * rs), q1 = f2bf(v1 * rs);
  Q[(size_t)row * LDIM + t] = q0;
  Q[(size_t)row * LDIM + t + 256] = q1;
  if (row >= NTOK) {
    // b2 from the bf16-rounded values (consistent with the MFMA dot)
    float f0 = bf2f(q0), f1 = bf2f(q1);
    float s2 = fmaf(f0, f0, f1 * f1);
#pragma unroll
    for (int o = 32; o > 0; o >>= 1) s2 += __shfl_down(s2, o, 64);
    __syncthreads();
    if (lane == 0) red[wid] = s2;
    __syncthreads();
    if (t == 0) b2[row - NTOK] = red[0] + red[1] + red[2] + red[3];
  }
}

// ---------------- distance GEMM (MFMA bf16) + fused argmin ----------------
// key(n,v) = b2[v] - 2 * <Qin[n], Qcb[v]>. Per-block partial argmin written to
// part[n*128 + bx*2 + wn] (no atomics).
__global__ __launch_bounds__(256)
void k_dist(const ushort_t* __restrict__ Q, const float* __restrict__ b2,
            u64* __restrict__ part) {
  __shared__ __align__(16) ushort_t As[128 * 32];
  __shared__ __align__(16) ushort_t Bs[128 * 32];
  const int t = threadIdx.x;
  const int wave = t >> 6, lane = t & 63;
  const int v0 = blockIdx.x * 128;  // codebook block
  const int n0 = blockIdx.y * 128;  // token block
  const ushort_t* Qa = Q + (size_t)n0 * LDIM;
  const ushort_t* Qb = Q + (size_t)(NTOK + v0) * LDIM;

  const int srow = lane >> 2;
  const int sg = (lane & 3) ^ (srow & 3) ^ ((srow >> 2) & 3);
  const int r0a = wave * 16, r0b = 64 + wave * 16;
  const ushort_t* apA = Qa + (size_t)(r0a + srow) * LDIM + sg * 8;
  const ushort_t* apB = Qa + (size_t)(r0b + srow) * LDIM + sg * 8;
  const ushort_t* bpA = Qb + (size_t)(r0a + srow) * LDIM + sg * 8;
  const ushort_t* bpB = Qb + (size_t)(r0b + srow) * LDIM + sg * 8;
  char* awA = (char*)As + r0a * 64;
  char* awB = (char*)As + r0b * 64;
  char* bwA = (char*)Bs + r0a * 64;
  char* bwB = (char*)Bs + r0b * 64;

  const int wm = wave >> 1, wn = wave & 1;
  const int m = lane & 15, q = lane >> 4;
  const int pq = (q ^ (m & 3) ^ ((m >> 2) & 3)) * 16;

  f32x4 acc[4][4];
#pragma unroll
  for (int i = 0; i < 4; ++i)
#pragma unroll
    for (int j = 0; j < 4; ++j) acc[i][j] = (f32x4)(0.f);

  for (int k0 = 0; k0 < LDIM; k0 += 32) {
    __syncthreads();
    gload_lds16(apA + k0, awA);
    gload_lds16(apB + k0, awB);
    gload_lds16(bpA + k0, bwA);
    gload_lds16(bpB + k0, bwB);
    __syncthreads();
    s16x8 af[4], bfr[4];
#pragma unroll
    for (int i = 0; i < 4; ++i)
      af[i] = *(const s16x8*)((const char*)As + (wm * 64 + i * 16 + m) * 64 + pq);
#pragma unroll
    for (int j = 0; j < 4; ++j)
      bfr[j] = *(const s16x8*)((const char*)Bs + (wn * 64 + j * 16 + m) * 64 + pq);
#pragma unroll
    for (int i = 0; i < 4; ++i)
#pragma unroll
      for (int j = 0; j < 4; ++j)
        acc[i][j] = mfma16(af[i], bfr[j], acc[i][j]);
  }

  float b2v[4];
#pragma unroll
  for (int j = 0; j < 4; ++j) b2v[j] = b2[v0 + wn * 64 + j * 16 + m];

#pragma unroll
  for (int i = 0; i < 4; ++i)
#pragma unroll
    for (int reg = 0; reg < 4; ++reg) {
      float bk = 1e30f;
      int bvi = 0;
#pragma unroll
      for (int j = 0; j < 4; ++j) {
        int col = v0 + wn * 64 + j * 16 + m;
        float key = fmaf(-2.f, acc[i][j][reg], b2v[j]);
        if (key < bk) { bk = key; bvi = col; }
      }
      u64 pk = (((u64)key_of(bk)) << 32) | (unsigned)bvi;
#pragma unroll
      for (int msk = 1; msk < 16; msk <<= 1) {
        u64 o = shfl_xor_u64(pk, msk, 16);
        if (o < pk) pk = o;
      }
      if (m == 0) {
        int row = n0 + wm * 64 + i * 16 + q * 4 + reg;
        part[(size_t)row * 128 + blockIdx.x * 2 + wn] = pk;
      }
    }
}

// ---------------- argmin reduce over 128 partials per row ----------------
__global__ __launch_bounds__(256)
void k_reduce(const u64* __restrict__ part, int* __restrict__ idx,
              int* __restrict__ hist) {
  const int n = blockIdx.x * 4 + (threadIdx.x >> 6);
  const int lane = threadIdx.x & 63;
  u64 p0 = part[(size_t)n * 128 + lane];
  u64 p1 = part[(size_t)n * 128 + 64 + lane];
  u64 pk = (p1 < p0) ? p1 : p0;
#pragma unroll
  for (int msk = 1; msk < 64; msk <<= 1) {
    u64 o = shfl_xor_u64(pk, msk, 64);
    if (o < pk) pk = o;
  }
  if (lane == 0) {
    int iv = (int)(pk & 0xffffffffull);
    idx[n] = iv;
    atomicAdd(&hist[iv], 1);
  }
}

// ---------------- gather + loss partials ----------------
__global__ __launch_bounds__(256)
void k_gather(const int* __restrict__ idx, const float* __restrict__ cb,
              const float* __restrict__ x, const float* __restrict__ P,
              float* __restrict__ out, float* __restrict__ partq,
              float* __restrict__ partl) {
  const int n = blockIdx.x;
  const int t = threadIdx.x;
  const int lane = t & 63, wid = t >> 6;
  __shared__ float rq[4], rl[4];
  const int iv = idx[n];
  // quantized row copy + commit MSE partial
  float4 qv = *(const float4*)&cb[(size_t)iv * DDIM + t * 4];
  float4 xv = *(const float4*)&x[(size_t)n * DDIM + t * 4];
  *(float4*)&out[(size_t)n * DDIM + t * 4] = qv;
  float d0 = qv.x - xv.x, d1 = qv.y - xv.y, d2 = qv.z - xv.z, d3 = qv.w - xv.w;
  float sq = d0 * d0 + d1 * d1 + d2 * d2 + d3 * d3;
  // latent MSE partial: latent_quantized = P_code[iv], latent_x = P_in[n]
  float2 lq = *(const float2*)&P[(size_t)(NTOK + iv) * LDIM + t * 2];
  float2 lx = *(const float2*)&P[(size_t)n * LDIM + t * 2];
  float e0 = lq.x - lx.x, e1 = lq.y - lx.y;
  float sl = e0 * e0 + e1 * e1;
#pragma unroll
  for (int o = 32; o > 0; o >>= 1) {
    sq += __shfl_down(sq, o, 64);
    sl += __shfl_down(sl, o, 64);
  }
  if (lane == 0) { rq[wid] = sq; rl[wid] = sl; }
  __syncthreads();
  if (t == 0) {
    partq[n] = rq[0] + rq[1] + rq[2] + rq[3];
    partl[n] = rl[0] + rl[1] + rl[2] + rl[3];
  }
}

// ---------------- finalize scalars ----------------
__global__ __launch_bounds__(1024)
void k_final(const int* __restrict__ hist, const float* __restrict__ partq,
             const float* __restrict__ partl, float* __restrict__ out) {
  const int t = threadIdx.x;
  const int lane = t & 63, wid = t >> 6;  // 16 waves
  float perp = 0.f, usedf = 0.f, sq = 0.f, sl = 0.f;
  for (int v = t; v < VCB; v += 1024) {
    int h = hist[v];
    usedf += (h > 0) ? 1.f : 0.f;
    float p = (float)h * (1.f / (float)NTOK);
    perp -= p * logf(p + 1e-10f);
  }
  for (int n = t; n < NTOK; n += 1024) {
    sq += partq[n];
    sl += partl[n];
  }
#pragma unroll
  for (int o = 32; o > 0; o >>= 1) {
    perp  += __shfl_down(perp, o, 64);
    usedf += __shfl_down(usedf, o, 64);
    sq    += __shfl_down(sq, o, 64);
    sl    += __shfl_down(sl, o, 64);
  }
  __shared__ float red[16][4];
  if (lane == 0) {
    red[wid][0] = perp; red[wid][1] = usedf; red[wid][2] = sq; red[wid][3] = sl;
  }
  __syncthreads();
  if (t == 0) {
    float Pp = 0.f, U = 0.f, SQ = 0.f, SL = 0.f;
    for (int w = 0; w < 16; ++w) {
      Pp += red[w][0]; U += red[w][1]; SQ += red[w][2]; SL += red[w][3];
    }
    float mseq = SQ / (float)((size_t)NTOK * DDIM);
    float msel = SL / (float)((size_t)NTOK * LDIM);
    float loss = 1.25f * mseq + 1.25f * msel + 0.1f * Pp;
    out[(size_t)NTOK * DDIM + 0] = loss;
    out[(size_t)NTOK * DDIM + 1] = expf(Pp);
    out[(size_t)NTOK * DDIM + 2] = U / (float)VCB;
  }
}

extern "C" void kernel_launch(void* const* d_in, const int* in_sizes, int n_in,
                              void* d_out, int out_size, void* d_ws, size_t ws_size,
                              hipStream_t stream) {
  const float* x  = (const float*)d_in[0];
  const float* cb = (const float*)d_in[1];
  const float* Wi = (const float*)d_in[2];
  const float* bi = (const float*)d_in[3];
  const float* Wc = (const float*)d_in[4];
  const float* bc = (const float*)d_in[5];
  float* out = (float*)d_out;
  char* ws = (char*)d_ws;
  float*    P    = (float*)(ws + OFF_P);
  ushort_t* Q    = (ushort_t*)(ws + OFF_Q);
  ushort_t* Wt   = (ushort_t*)(ws + OFF_WT);
  float*    b2   = (float*)(ws + OFF_B2);
  u64*      part = (u64*)(ws + OFF_PART);
  int*      idx  = (int*)(ws + OFF_IDX);
  int*      hist = (int*)(ws + OFF_HIST);
  float*    partq = (float*)(ws + OFF_PARTQ);
  float*    partl = (float*)(ws + OFF_PARTL);

  hipLaunchKernelGGL(k_init, dim3(32), dim3(256), 0, stream, hist);
  hipLaunchKernelGGL(k_wt, dim3(DDIM / 32, LDIM / 32, 2), dim3(32, 8), 0,
                     stream, Wi, Wc, Wt);
  hipLaunchKernelGGL(k_latent, dim3(LDIM / 128, MROWS / 128), dim3(256), 0,
                     stream, x, cb, Wt, bi, bc, P);
  hipLaunchKernelGGL(k_rownorm, dim3(MROWS), dim3(256), 0, stream, P, Q, b2);
  hipLaunchKernelGGL(k_dist, dim3(VCB / 128, NTOK / 128), dim3(256), 0, stream,
                     Q, b2, part);
  hipLaunchKernelGGL(k_reduce, dim3(NTOK / 4), dim3(256), 0, stream, part, idx,
                     hist);
  hipLaunchKernelGGL(k_gather, dim3(NTOK), dim3(256), 0, stream, idx, cb, x, P,
                     out, partq, partl);
  hipLaunchKernelGGL(k_final, dim3(1), dim3(1024), 0, stream, hist, partq,
                     partl, out);
}